// Round 5
// baseline (272.501 us; speedup 1.0000x reference)
//
#include <hip/hip_runtime.h>

// MorphoMLP: y = relu(maxplus(relu(maxplus(x,W1)), W2)), fp32.
// B=512, IN=512, HID=1024, OUT=512.
// R5: split-K partials eliminated via uint atomicMax (valid: outputs >= 0
//     after relu, and uint ordering == float ordering for non-negatives).
//     Balanced frag 8x8 (1.0 B/pos LDS vs 85 B/cyc), Kchunk=32, grid 512,
//     32KB LDS, 2 blocks/CU.
//   memset(h,yT) -> transpose3 -> morphoA<1024> (h[j][b] += atomic)
//   -> morphoA<512> (yT[o][b]) -> transposeY
// ws: h 2MB | yT 1MB | xT 1MB | W1T 2MB | W2T 2MB = 8MB

#define WS_H    0                         // [1024][512]  h[j][b] = relu(L1)
#define WS_YT   (1024 * 512)              // [512][512]   yT[o][b] = relu(L2)
#define WS_XT   (WS_YT + 512 * 512)       // [512][512]   x^T  [k][b]
#define WS_W1T  (WS_XT + 512 * 512)       // [512][1024]  W1^T [k][j]
#define WS_W2T  (WS_W1T + 512 * 1024)     // [1024][512]  W2^T [k2][o]

// ---------------------------------------------------------------------------
// Fused transpose of x (512x512), W1 (1024x512), W2 (512x1024) into ws.
__global__ __launch_bounds__(256) void transpose3(const float* __restrict__ x,
                                                  const float* __restrict__ W1,
                                                  const float* __restrict__ W2,
                                                  float* __restrict__ ws) {
    __shared__ float t[32][33];
    const int id = blockIdx.x;
    const float* src;
    float* dst;
    int R, C, rt, ct;
    if (id < 256) {
        src = x;  dst = ws + WS_XT;  R = 512;  C = 512;
        rt = id >> 4;          ct = id & 15;
    } else if (id < 768) {
        int b = id - 256;
        src = W1; dst = ws + WS_W1T; R = 1024; C = 512;
        rt = b >> 4;           ct = b & 15;
    } else {
        int b = id - 768;
        src = W2; dst = ws + WS_W2T; R = 512;  C = 1024;
        rt = b >> 5;           ct = b & 31;
    }
    const int tx = threadIdx.x & 31, ty = threadIdx.x >> 5;
    const int r0 = rt * 32, c0 = ct * 32;
#pragma unroll
    for (int r = 0; r < 4; r++)
        t[ty + 8 * r][tx] = src[(size_t)(r0 + ty + 8 * r) * C + c0 + tx];
    __syncthreads();
#pragma unroll
    for (int r = 0; r < 4; r++)
        dst[(size_t)(c0 + ty + 8 * r) * R + r0 + tx] = t[tx][ty + 8 * r];
}

// ---------------------------------------------------------------------------
// Max-plus tile kernel: 128j x 128b tile, 32-k single stage, 8x8 frag/thread.
// A: [K][512] K-major activations; W: [K][JDIM] K-major weights.
// Epilogue: clamp at 0 (relu) and uint-atomicMax into O[j][b] (ld 512).
// O must be zero-initialized; result is exact (max is order-insensitive).
template <int JDIM>
__global__ __launch_bounds__(256, 2) void morphoA(const float* __restrict__ A,
                                                  const float* __restrict__ W,
                                                  float* __restrict__ O) {
    __shared__ float lA[32 * 128];   // [k][b]  16KB
    __shared__ float lW[32 * 128];   // [k][j]  16KB
    const int t  = threadIdx.x;
    const int tx = t & 15;           // b frag: b0 + tx*4 + {0..3} and +64
    const int ty = t >> 4;           // j frag: j0 + ty*4 + {0..3} and +64
    const int j0 = blockIdx.x * 128;
    const int b0 = blockIdx.y * 128;
    const int k0 = blockIdx.z * 32;

    // ---- stage A and W tiles: 1024 float4 each, 4/thread each ----
#pragma unroll
    for (int r = 0; r < 4; r++) {
        const int q  = t + 256 * r;       // 0..1023
        const int kk = q >> 5, c = q & 31;
        ((float4*)lA)[q] = *((const float4*)(A + (size_t)(k0 + kk) * 512 + b0) + c);
        ((float4*)lW)[q] = *((const float4*)(W + (size_t)(k0 + kk) * JDIM + j0) + c);
    }
    __syncthreads();

    float acc[8][8];
#pragma unroll
    for (int jj = 0; jj < 8; jj++)
#pragma unroll
        for (int ii = 0; ii < 8; ii++) acc[jj][ii] = -3.402823466e38f;

    const float4* lA4 = (const float4*)lA;
    const float4* lW4 = (const float4*)lW;

    // ---- inner max-plus: 2 k's per iter so fmax pairs fuse to v_max3 ----
#pragma unroll 2
    for (int kk = 0; kk < 32; kk += 2) {
        float a0[8], a1[8], w0[8], w1[8];
        *(float4*)(a0)     = lA4[kk * 32 + tx];
        *(float4*)(a0 + 4) = lA4[kk * 32 + 16 + tx];
        *(float4*)(w0)     = lW4[kk * 32 + ty];
        *(float4*)(w0 + 4) = lW4[kk * 32 + 16 + ty];
        *(float4*)(a1)     = lA4[kk * 32 + 32 + tx];
        *(float4*)(a1 + 4) = lA4[kk * 32 + 48 + tx];
        *(float4*)(w1)     = lW4[kk * 32 + 32 + ty];
        *(float4*)(w1 + 4) = lW4[kk * 32 + 48 + ty];
#pragma unroll
        for (int jj = 0; jj < 8; jj++)
#pragma unroll
            for (int ii = 0; ii < 8; ii++)
                acc[jj][ii] =
                    fmaxf(fmaxf(acc[jj][ii], a0[ii] + w0[jj]), a1[ii] + w1[jj]);
    }

    // ---- epilogue: relu-clamp + atomicMax (uint order == float order, >=0) --
#pragma unroll
    for (int jj = 0; jj < 8; jj++) {
        const int j = j0 + (jj < 4 ? ty * 4 + jj : 64 + ty * 4 + (jj - 4));
        unsigned int* row = (unsigned int*)(O + (size_t)j * 512);
#pragma unroll
        for (int ii = 0; ii < 8; ii++) {
            const int b = b0 + (ii < 4 ? tx * 4 + ii : 64 + tx * 4 + (ii - 4));
            const float v = fmaxf(acc[jj][ii], 0.0f);
            atomicMax(row + b, __float_as_uint(v));
        }
    }
}

// ---------------------------------------------------------------------------
// transposeY: out[b][o] = yT[o][b]  (yT already relu'd via zero-init+clamp).
__global__ __launch_bounds__(256) void transposeY(const float* __restrict__ yT,
                                                  float* __restrict__ out) {
    __shared__ float t[32][33];
    const int id = blockIdx.x;
    const int ot = id & 15, bt = id >> 4;
    const int tx = threadIdx.x & 31, ty = threadIdx.x >> 5;
    const int o0 = ot * 32, b0 = bt * 32;
#pragma unroll
    for (int r = 0; r < 4; r++)
        t[ty + 8 * r][tx] = yT[(o0 + ty + 8 * r) * 512 + b0 + tx];
    __syncthreads();
#pragma unroll
    for (int r = 0; r < 4; r++)
        out[(b0 + ty + 8 * r) * 512 + o0 + tx] = t[tx][ty + 8 * r];
}

// ---------------------------------------------------------------------------
extern "C" void kernel_launch(void* const* d_in, const int* in_sizes, int n_in,
                              void* d_out, int out_size, void* d_ws, size_t ws_size,
                              hipStream_t stream) {
    (void)in_sizes; (void)n_in; (void)out_size; (void)ws_size;
    const float* x  = (const float*)d_in[0];
    const float* W1 = (const float*)d_in[1];
    const float* W2 = (const float*)d_in[2];
    float* ws  = (float*)d_ws;
    float* out = (float*)d_out;

    // 0) zero h and yT (contiguous 3 MB) — required for atomicMax/relu
    hipMemsetAsync(ws, 0, (size_t)(1024 * 512 + 512 * 512) * sizeof(float),
                   stream);

    // 1) K-major transposes of x, W1, W2
    transpose3<<<1280, 256, 0, stream>>>(x, W1, W2, ws);

    // 2) L1: h[j][b] = relu(maxplus); grid 8(j) x 4(b) x 16(kz) = 512 blocks
    morphoA<1024><<<dim3(8, 4, 16), 256, 0, stream>>>(
        ws + WS_XT, ws + WS_W1T, ws + WS_H);

    // 3) L2: yT[o][b] = relu(maxplus); grid 4(j) x 4(b) x 32(kz) = 512 blocks
    morphoA<512><<<dim3(4, 4, 32), 256, 0, stream>>>(
        ws + WS_H, ws + WS_W2T, ws + WS_YT);

    // 4) transpose yT -> d_out[b][o]
    transposeY<<<256, 256, 0, stream>>>(ws + WS_YT, out);
}

// Round 6
// 98.589 us; speedup vs baseline: 2.7640x; 2.7640x over previous
//
#include <hip/hip_runtime.h>

// MorphoMLP: y = relu(maxplus(relu(maxplus(x,W1)), W2)), fp32 in/out.
// B=512, IN=512, HID=1024, OUT=512.
// R6: packed-fp16 data path (v_pk_add_f16 + v_pk_max_f16, 2 elems/inst).
//     acc init = 0 fuses ReLU exactly (max(0,.) distributes over split-K).
//     Tile 128j x 128b, frag 8x8 (contiguous 8 -> 1 ds_read_b128 per frag),
//     Kchunk=32, grid 512 = 2 blocks/CU, 16KB LDS.
//   transpose3(fp32->fp16 K-major) -> morphoH<1024> (z=16, fp16 partials)
//   -> combineH (max16) -> morphoH<512> (z=32) -> combineY (max32 -> fp32 + T)
// Precision: |candidates| <= ~6; fp16 err ~5e-3/layer << 0.111 threshold.

typedef _Float16 h2 __attribute__((ext_vector_type(2)));
typedef _Float16 h8 __attribute__((ext_vector_type(8)));

// ws offsets in _Float16 elements
#define HXT   0                         // [512][512]   x^T  [k][b]
#define HW1T  (512 * 512)               // [512][1024]  W1^T [k][j]
#define HW2T  (HW1T + 512 * 1024)       // [1024][512]  W2^T [k2][o]
#define HA2   (HW2T + 1024 * 512)       // [1024][512]  relu(h)^T [k2][b]
#define HHP   (HA2 + 1024 * 512)        // [16][1024][512]  L1 partials
#define HYP   (HHP + 16 * 1024 * 512)   // [32][512][512]   L2 partials

// ---------------------------------------------------------------------------
// Fused transpose+convert of x (512x512), W1 (1024x512), W2 (512x1024).
__global__ __launch_bounds__(256) void transpose3(const float* __restrict__ x,
                                                  const float* __restrict__ W1,
                                                  const float* __restrict__ W2,
                                                  _Float16* __restrict__ ws) {
    __shared__ float t[32][33];
    const int id = blockIdx.x;
    const float* src;
    _Float16* dst;
    int R, C, rt, ct;
    if (id < 256) {
        src = x;  dst = ws + HXT;  R = 512;  C = 512;
        rt = id >> 4;          ct = id & 15;
    } else if (id < 768) {
        int b = id - 256;
        src = W1; dst = ws + HW1T; R = 1024; C = 512;
        rt = b >> 4;           ct = b & 15;
    } else {
        int b = id - 768;
        src = W2; dst = ws + HW2T; R = 512;  C = 1024;
        rt = b >> 5;           ct = b & 31;
    }
    const int tx = threadIdx.x & 31, ty = threadIdx.x >> 5;
    const int r0 = rt * 32, c0 = ct * 32;
#pragma unroll
    for (int r = 0; r < 4; r++)
        t[ty + 8 * r][tx] = src[(size_t)(r0 + ty + 8 * r) * C + c0 + tx];
    __syncthreads();
#pragma unroll
    for (int r = 0; r < 4; r++)
        dst[(size_t)(c0 + ty + 8 * r) * R + r0 + tx] =
            (_Float16)t[tx][ty + 8 * r];
}

// ---------------------------------------------------------------------------
// Packed-fp16 max-plus tile: 128j x 128b, 32-k single stage, 8x8 frag.
// A: [K][512] fp16 K-major; W: [K][JDIM] fp16 K-major.
// acc init 0 == fused relu (valid per split-K distributivity).
// Partial P[z][j][b] fp16. Frag = 8 CONTIGUOUS j / b -> 1 b128 read each.
template <int JDIM>
__global__ __launch_bounds__(256, 2) void morphoH(const _Float16* __restrict__ A,
                                                  const _Float16* __restrict__ W,
                                                  _Float16* __restrict__ P) {
    __shared__ _Float16 lA[32 * 128];   // [k][b]  8KB
    __shared__ _Float16 lW[32 * 128];   // [k][j]  8KB
    const int t  = threadIdx.x;
    const int tx = t & 15;              // b frag: b0 + tx*8 + {0..7}
    const int ty = t >> 4;              // j frag: j0 + ty*8 + {0..7}
    const int j0 = blockIdx.x * 128;
    const int b0 = blockIdx.y * 128;
    const int k0 = blockIdx.z * 32;

    // ---- stage A and W tiles: 512 x 16B slots each, 2/thread each ----
#pragma unroll
    for (int r = 0; r < 2; r++) {
        const int q  = t + 256 * r;     // 0..511
        const int kk = q >> 4, c = q & 15;
        ((float4*)lA)[q] = *((const float4*)(A + (size_t)(k0 + kk) * 512 + b0) + c);
        ((float4*)lW)[q] = *((const float4*)(W + (size_t)(k0 + kk) * JDIM + j0) + c);
    }
    __syncthreads();

    h2 acc[8][4];
#pragma unroll
    for (int jj = 0; jj < 8; jj++)
#pragma unroll
        for (int bb = 0; bb < 4; bb++) acc[jj][bb] = (h2)(_Float16)0.0f;

    const float4* lA4 = (const float4*)lA;
    const float4* lW4 = (const float4*)lW;

#pragma unroll 8
    for (int kk = 0; kk < 32; kk++) {
        float4 a4 = lA4[kk * 16 + tx];          // 8 b-halves (1 ds_read_b128)
        float4 w4 = lW4[kk * 16 + ty];          // 8 j-halves (broadcast)
        const h2* ah = (const h2*)&a4;
        const _Float16* wf = (const _Float16*)&w4;
#pragma unroll
        for (int jj = 0; jj < 8; jj++) {
            const h2 wd = {wf[jj], wf[jj]};
#pragma unroll
            for (int bb = 0; bb < 4; bb++) {
                const h2 s = ah[bb] + wd;                     // v_pk_add_f16
                acc[jj][bb] = __builtin_elementwise_max(acc[jj][bb], s);  // v_pk_max_f16
            }
        }
    }

    // ---- store fp16 partial: P[z][j][b], 16B contiguous per thread-row ----
    _Float16* Pp = P + (size_t)blockIdx.z * JDIM * 512;
#pragma unroll
    for (int jj = 0; jj < 8; jj++) {
        float4 st;
        h2* sp = (h2*)&st;
#pragma unroll
        for (int bb = 0; bb < 4; bb++) sp[bb] = acc[jj][bb];
        *(float4*)(Pp + (size_t)(j0 + ty * 8 + jj) * 512 + b0 + tx * 8) = st;
    }
}

// ---------------------------------------------------------------------------
// combineH: A2[j][b] = max_z hp[z][j][b]  (relu already fused via acc=0).
// 512K halves = 64K h8 slots; 256 blocks x 256 thr x 1 slot.
__global__ __launch_bounds__(256) void combineH(const _Float16* __restrict__ hp,
                                                _Float16* __restrict__ A2) {
    const int i = blockIdx.x * 256 + threadIdx.x;   // h8 slot
    const h8* p = (const h8*)hp;
    h8 m = p[i];
#pragma unroll
    for (int z = 1; z < 16; z++)
        m = __builtin_elementwise_max(m, p[i + z * 65536]);  // 512K/8 per z
    ((h8*)A2)[i] = m;
}

// ---------------------------------------------------------------------------
// combineY: out[b][o] (fp32) = max_z yp[z][o][b] (fp16), z<32; + transpose.
// Block: 32 o x 64 b. Grid 16(o) x 8(b) = 128 blocks.
__global__ __launch_bounds__(256) void combineY(const _Float16* __restrict__ yp,
                                                float* __restrict__ out) {
    __shared__ float ts[32][65];
    const int t  = threadIdx.x;
    const int tx = t & 31;          // b-pair: b_local = tx*2
    const int ty = t >> 5;          // o rows: ty, ty+8, ty+16, ty+24
    const int o0 = blockIdx.x * 32;
    const int b0 = blockIdx.y * 64;
#pragma unroll
    for (int r = 0; r < 4; r++) {
        const int ol = ty + 8 * r;
        const size_t idx = (size_t)(o0 + ol) * 512 + b0 + tx * 2;
        h2 m = *(const h2*)(yp + idx);
#pragma unroll
        for (int z = 1; z < 32; z++)
            m = __builtin_elementwise_max(m, *(const h2*)(yp + idx + (size_t)z * 262144));
        ts[ol][tx * 2]     = (float)m.x;
        ts[ol][tx * 2 + 1] = (float)m.y;
    }
    __syncthreads();
    // write out[b][o]: thread -> b_local = t>>2 (64 rows), o chunk (t&3)*8
    const int bl = t >> 2, oc = (t & 3) * 8;
    float v[8];
#pragma unroll
    for (int i = 0; i < 8; i++) v[i] = ts[oc + i][bl];
    float* op = out + (size_t)(b0 + bl) * 512 + o0 + oc;
    *(float4*)(op)     = make_float4(v[0], v[1], v[2], v[3]);
    *(float4*)(op + 4) = make_float4(v[4], v[5], v[6], v[7]);
}

// ---------------------------------------------------------------------------
extern "C" void kernel_launch(void* const* d_in, const int* in_sizes, int n_in,
                              void* d_out, int out_size, void* d_ws, size_t ws_size,
                              hipStream_t stream) {
    (void)in_sizes; (void)n_in; (void)out_size; (void)ws_size;
    const float* x  = (const float*)d_in[0];
    const float* W1 = (const float*)d_in[1];
    const float* W2 = (const float*)d_in[2];
    _Float16* ws = (_Float16*)d_ws;
    float* out = (float*)d_out;

    // 1) K-major fp16 transposes of x, W1, W2
    transpose3<<<1280, 256, 0, stream>>>(x, W1, W2, ws);

    // 2) L1: hp[16][1024][512]; grid 8(j) x 4(b) x 16(kz) = 512 blocks (2/CU)
    morphoH<1024><<<dim3(8, 4, 16), 256, 0, stream>>>(
        ws + HXT, ws + HW1T, ws + HHP);

    // 3) combine 16 partials -> A2[k2][b] (relu already fused)
    combineH<<<256, 256, 0, stream>>>(ws + HHP, ws + HA2);

    // 4) L2: yp[32][512][512]; grid 4(j) x 4(b) x 32(kz) = 512 blocks (2/CU)
    morphoH<512><<<dim3(4, 4, 32), 256, 0, stream>>>(
        ws + HA2, ws + HW2T, ws + HYP);

    // 5) combine 32 partials + transpose + fp32 convert -> d_out[b][o]
    combineY<<<dim3(16, 8), 256, 0, stream>>>(ws + HYP, out);
}